// Round 4
// baseline (96.132 us; speedup 1.0000x reference)
//
#include <hip/hip_runtime.h>

// Problem constants (from reference)
#define NF 10000
#define LL 100000

typedef float f32x2 __attribute__((ext_vector_type(2)));
typedef float f32x4 __attribute__((ext_vector_type(4)));

constexpr int BC    = 64;                      // B*C
constexpr int TL    = 64;                      // l's per main block
constexpr int NBLK  = (LL + TL - 1) / TL;      // 1563
constexpr int BLOCK = 512;                     // 8 waves
constexpr int NW    = BLOCK / 64;
constexpr int CSTR  = 65;                      // corr [bc][slot] stride (float2)

constexpr int TNF   = 32;                      // nf rows per transpose block
constexpr int TBLK  = (NF + TNF - 1) / TNF;    // 313

// workspace layout
constexpr size_t WS_ACC  = 0;     // double
constexpr size_t WS_DONE = 8;     // int
constexpr size_t WS_TBL  = 256;   // NF*64 float4 = 10,240,000 B
constexpr size_t WS_NEED = WS_TBL + (size_t)NF * BC * 16;

// ---------- prep: transpose (fgap, t_f) into packed [nf][bc] float4 rows ----------
__global__ __launch_bounds__(256) void prep_t(
    const float2* __restrict__ i_f, const float2* __restrict__ t_f,
    f32x4* __restrict__ tbl)
{
    __shared__ f32x4 t4[BC][TNF + 1];
    const int nf0  = blockIdx.x * TNF;
    const int nrem = min(TNF, NF - nf0);
    const int c = threadIdx.x & 31;   // nf within tile
    const int r = threadIdx.x >> 5;   // 0..7 bc start
    if (c < nrem) {
        for (int bc = r; bc < BC; bc += 8) {
            float2 iv = i_f[(size_t)bc * NF + nf0 + c];
            float2 tv = t_f[(size_t)bc * NF + nf0 + c];
            t4[bc][c] = (f32x4){iv.x - tv.x, iv.y - tv.y, tv.x, tv.y};
        }
    }
    __syncthreads();
    const int lane = threadIdx.x & 63;  // bc
    const int w    = threadIdx.x >> 6;  // 0..3
    for (int j = w; j < nrem; j += 4)
        tbl[(size_t)(nf0 + j) * BC + lane] = t4[lane][j];
}

// ---------- main: compact + coalesced gather + coalesced streams + fused finalize ----------
__global__ __launch_bounds__(BLOCK) void mse_main3(
    const float* __restrict__ i_s, const float* __restrict__ t_s,
    const int2*  __restrict__ xi,  const float2* __restrict__ ks,
    const f32x4* __restrict__ tbl,
    double* __restrict__ acc, int* __restrict__ done, float* __restrict__ out)
{
    __shared__ float2 corr[BC * CSTR];   // [bc][slot]
    __shared__ int2   xi_list[TL];
    __shared__ int    pos[TL];
    __shared__ int    cnt;
    __shared__ float  wsum[NW];

    const int l0   = blockIdx.x * TL;
    const int tlb  = min(TL, LL - l0);
    const int tid  = threadIdx.x;
    const int lane = tid & 63;
    const int wid  = tid >> 6;

    if (tid == 0) cnt = 0;
    if (tid < TL) pos[tid] = -1;
    __syncthreads();

    // classify + compact active l's (both correction masks false)
    if (tid < tlb) {
        float2 k = ks[l0 + tid];
        if (!(k.x > 0.f) && !(k.y > 0.f)) {
            int slot = atomicAdd(&cnt, 1);
            pos[tid] = slot;
            xi_list[slot] = xi[l0 + tid];
        }
    }
    __syncthreads();

    // per active slot: one wave reads 2 coalesced 1KB float4 rows, computes corr[bc]
    const int nact = cnt;
    for (int a = wid; a < nact; a += NW) {
        int2 idx = xi_list[a];
        f32x4 r0 = tbl[(size_t)idx.x * BC + lane];  // (f0, tf0)
        f32x4 r1 = tbl[(size_t)idx.y * BC + lane];  // (f1, tf1)
        // corr = cmul_conj(f0,tf1) + cmul_conj(tf0,f1)
        float cr = r0.x * r1.z + r0.y * r1.w + r0.z * r1.x + r0.w * r1.y;
        float ci = r0.y * r1.z - r0.x * r1.w + r0.w * r1.x - r0.z * r1.y;
        corr[lane * CSTR + a] = make_float2(cr, ci);
    }
    __syncthreads();

    // streams: lane <-> l (coalesced 512B), unrolled bc loop for ILP
    float sum = 0.f;
    if (lane < tlb) {
        const int l = l0 + lane;
        const int myslot = pos[lane];
        #pragma unroll
        for (int it = 0; it < BC / NW; ++it) {
            const int bc = wid + it * NW;
            f32x2 si = __builtin_nontemporal_load((const f32x2*)(i_s + 2 * ((size_t)bc * LL + l)));
            f32x2 st = __builtin_nontemporal_load((const f32x2*)(t_s + 2 * ((size_t)bc * LL + l)));
            float gr = si.x - st.x;
            float gi = si.y - st.y;
            if (myslot >= 0) {
                float2 cc = corr[bc * CSTR + myslot];
                gr -= cc.x;
                gi -= cc.y;
            }
            sum += gr * gr + gi * gi;
        }
    }

    #pragma unroll
    for (int off = 32; off; off >>= 1) sum += __shfl_down(sum, off, 64);
    if (lane == 0) wsum[wid] = sum;
    __syncthreads();
    if (tid == 0) {
        float t = 0.f;
        #pragma unroll
        for (int i = 0; i < NW; ++i) t += wsum[i];
        atomicAdd(acc, (double)t);
        __threadfence();
        int prev = atomicAdd(done, 1);
        if (prev == NBLK - 1) {
            double total = atomicAdd(acc, 0.0);   // device-scope read of final sum
            out[0] = (float)(total / (double)((size_t)BC * LL));
        }
    }
}

// ---------- fallback (round-1 kernel) if workspace too small ----------
constexpr int FCHUNKS = 32;
constexpr int FCHUNK  = (LL + FCHUNKS - 1) / FCHUNKS;

__global__ __launch_bounds__(256) void mse_fallback(
    const float* __restrict__ i_f, const float* __restrict__ i_s,
    const float* __restrict__ t_f, const float* __restrict__ t_s,
    const int*  __restrict__ xi,  const float* __restrict__ ks,
    double* __restrict__ acc)
{
    const int bc    = blockIdx.x / FCHUNKS;
    const int chunk = blockIdx.x % FCHUNKS;
    const int l0 = chunk * FCHUNK;
    const int l1 = (l0 + FCHUNK < LL) ? (l0 + FCHUNK) : LL;

    const float2* isv = (const float2*)i_s + (size_t)bc * LL;
    const float2* tsv = (const float2*)t_s + (size_t)bc * LL;
    const float2* ifv = (const float2*)i_f + (size_t)bc * NF;
    const float2* tfv = (const float2*)t_f + (size_t)bc * NF;
    const int2*   xiv = (const int2*)xi;
    const float2* ksv = (const float2*)ks;

    float sum = 0.f;
    for (int l = l0 + (int)threadIdx.x; l < l1; l += 256) {
        float2 si = isv[l], st = tsv[l];
        float gr = si.x - st.x, gi = si.y - st.y;
        float2 k = ksv[l];
        if (!(k.x > 0.f) && !(k.y > 0.f)) {
            int2 idx = xiv[l];
            float2 tf0 = tfv[idx.x], if0 = ifv[idx.x];
            float2 tf1 = tfv[idx.y], if1 = ifv[idx.y];
            float f0r = if0.x - tf0.x, f0i = if0.y - tf0.y;
            float f1r = if1.x - tf1.x, f1i = if1.y - tf1.y;
            gr -= f0r * tf1.x + f0i * tf1.y;
            gi -= f0i * tf1.x - f0r * tf1.y;
            gr -= tf0.x * f1r + tf0.y * f1i;
            gi -= tf0.y * f1r - tf0.x * f1i;
        }
        sum += gr * gr + gi * gi;
    }
    #pragma unroll
    for (int off = 32; off; off >>= 1) sum += __shfl_down(sum, off, 64);
    __shared__ float ws[4];
    const int lane = threadIdx.x & 63, wwid = threadIdx.x >> 6;
    if (lane == 0) ws[wwid] = sum;
    __syncthreads();
    if (threadIdx.x == 0) {
        float t = ws[0] + ws[1] + ws[2] + ws[3];
        atomicAdd(acc, (double)t);
    }
}

__global__ void mse_finalize(const double* __restrict__ acc, float* __restrict__ out)
{
    out[0] = (float)(acc[0] / (double)((size_t)BC * LL));
}

extern "C" void kernel_launch(void* const* d_in, const int* in_sizes, int n_in,
                              void* d_out, int out_size, void* d_ws, size_t ws_size,
                              hipStream_t stream)
{
    const float* i_f = (const float*)d_in[0];
    const float* i_s = (const float*)d_in[1];
    const float* t_f = (const float*)d_in[2];
    const float* t_s = (const float*)d_in[3];
    const int*   xi  = (const int*)d_in[4];
    const float* ks  = (const float*)d_in[5];
    float* out = (float*)d_out;

    char* ws = (char*)d_ws;
    double* acc = (double*)(ws + WS_ACC);
    int*   done = (int*)(ws + WS_DONE);
    (void)hipMemsetAsync(ws, 0, 16, stream);   // zero acc + done

    if (ws_size >= WS_NEED) {
        f32x4* tbl = (f32x4*)(ws + WS_TBL);
        prep_t<<<TBLK, 256, 0, stream>>>((const float2*)i_f, (const float2*)t_f, tbl);
        mse_main3<<<NBLK, BLOCK, 0, stream>>>(
            i_s, t_s, (const int2*)xi, (const float2*)ks, tbl, acc, done, out);
    } else {
        mse_fallback<<<BC * FCHUNKS, 256, 0, stream>>>(
            i_f, i_s, t_f, t_s, xi, ks, acc);
        mse_finalize<<<1, 1, 0, stream>>>(acc, out);
    }
}

// Round 5
// 83.211 us; speedup vs baseline: 1.1553x; 1.1553x over previous
//
#include <hip/hip_runtime.h>

// Problem constants (from reference)
#define NF 10000
#define LL 100000

typedef float f32x2 __attribute__((ext_vector_type(2)));
typedef float f32x4 __attribute__((ext_vector_type(4)));

constexpr int BC    = 64;                    // B*C
constexpr int TL    = 64;                    // l's per main block
constexpr int NBLK  = (LL + TL - 1) / TL;    // 1563
constexpr int BLOCK = 256;                   // 4 waves
constexpr int NW    = BLOCK / 64;            // 4
constexpr int NIT   = BC / NW;               // 16 bc-iterations per thread
constexpr int CSTR  = 65;                    // corr [bc][slot] stride (f32x2)

constexpr int TNF   = 16;                    // nf rows per prep block
constexpr int TBLK  = NF / TNF;              // 625 (exact)

// workspace layout
constexpr size_t WS_ACC  = 0;     // double
constexpr size_t WS_DONE = 8;     // int
constexpr size_t WS_TBL  = 256;   // NF*64 float4 = 10,240,000 B
constexpr size_t WS_NEED = WS_TBL + (size_t)NF * BC * 16;

// ---------- prep: transpose (fgap, t_f) into packed [nf][bc] float4 rows ----------
__global__ __launch_bounds__(256) void prep_t(
    const float2* __restrict__ i_f, const float2* __restrict__ t_f,
    f32x4* __restrict__ tbl, double* __restrict__ acc, int* __restrict__ done)
{
    __shared__ f32x4 t4[BC][TNF + 1];
    const int nf0 = blockIdx.x * TNF;
    const int tid = threadIdx.x;

    if (blockIdx.x == 0 && tid == 0) { *acc = 0.0; *done = 0; }

    const int c = tid & 15;          // nf within tile
    const int r = tid >> 4;          // bc start (0..15)
    for (int bc = r; bc < BC; bc += 16) {
        float2 iv = i_f[(size_t)bc * NF + nf0 + c];
        float2 tv = t_f[(size_t)bc * NF + nf0 + c];
        t4[bc][c] = (f32x4){iv.x - tv.x, iv.y - tv.y, tv.x, tv.y};
    }
    __syncthreads();
    const int lane = tid & 63;       // bc
    const int w    = tid >> 6;       // 0..3
    for (int j = w; j < TNF; j += 4)
        tbl[(size_t)(nf0 + j) * BC + lane] = t4[lane][j];
}

// ---------- main: bulk-issued stream loads + ballot classify + coalesced gather ----------
__global__ __launch_bounds__(BLOCK) void mse_main4(
    const float* __restrict__ i_s, const float* __restrict__ t_s,
    const int2*  __restrict__ xi,  const f32x2* __restrict__ ks,
    const f32x4* __restrict__ tbl,
    double* __restrict__ acc, int* __restrict__ done, float* __restrict__ out)
{
    __shared__ f32x2 corr[BC * CSTR];   // [bc][slot]
    __shared__ int2  xi_list[TL];
    __shared__ int   pos[TL];
    __shared__ int   cnt_s;
    __shared__ float wsum[NW];

    const int l0   = blockIdx.x * TL;
    const int tlb  = min(TL, LL - l0);
    const int tid  = threadIdx.x;
    const int lane = tid & 63;
    const int wid  = tid >> 6;
    const bool live = lane < tlb;
    const int l    = l0 + lane;

    // classify inputs first (wave 0 consumes them soonest)
    f32x2 kv = {1.f, 1.f};
    int2  idxv = {0, 0};
    if (wid == 0 && live) { kv = ks[l]; idxv = xi[l]; }

    // PASS 1: issue ALL stream loads into register arrays (bulk in-flight)
    f32x2 sa[NIT], sb[NIT];
    if (live) {
        #pragma unroll
        for (int it = 0; it < NIT; ++it) {
            const size_t off = ((size_t)(wid + it * NW) * LL + l) * 2;
            sa[it] = *(const f32x2*)(i_s + off);
            sb[it] = *(const f32x2*)(t_s + off);
        }
    } else {
        #pragma unroll
        for (int it = 0; it < NIT; ++it) { sa[it] = (f32x2){0.f, 0.f}; sb[it] = (f32x2){0.f, 0.f}; }
    }

    // wave-0 ballot classify + compaction (no LDS atomics)
    if (wid == 0) {
        const bool active = live && !(kv.x > 0.f) && !(kv.y > 0.f);
        const unsigned long long m = __ballot(active);
        const int slot = __popcll(m & ((1ull << lane) - 1ull));
        pos[lane] = active ? slot : -1;
        if (active) xi_list[slot] = idxv;
        if (lane == 0) cnt_s = (int)__popcll(m);
    }
    __syncthreads();   // drains the bulk loads once; classify results visible

    // gather: one wave reads 2 coalesced 1KB float4 table rows per active slot
    const int nact = cnt_s;
    for (int a = wid; a < nact; a += NW) {
        int2 idx = xi_list[a];
        f32x4 r0 = tbl[(size_t)idx.x * BC + lane];  // (f0, tf0)
        f32x4 r1 = tbl[(size_t)idx.y * BC + lane];  // (f1, tf1)
        // corr = cmul_conj(f0,tf1) + cmul_conj(tf0,f1)
        float cr = r0.x * r1.z + r0.y * r1.w + r0.z * r1.x + r0.w * r1.y;
        float ci = r0.y * r1.z - r0.x * r1.w + r0.w * r1.x - r0.z * r1.y;
        corr[lane * CSTR + a] = (f32x2){cr, ci};
    }
    __syncthreads();

    // PASS 2: consume from registers (no global memory on this path)
    float sum = 0.f;
    const int myslot = live ? pos[lane] : -1;
    if (myslot >= 0) {
        #pragma unroll
        for (int it = 0; it < NIT; ++it) {
            f32x2 cc = corr[(wid + it * NW) * CSTR + myslot];
            float r = (sa[it].x - sb[it].x) - cc.x;
            float q = (sa[it].y - sb[it].y) - cc.y;
            sum += r * r + q * q;
        }
    } else {
        #pragma unroll
        for (int it = 0; it < NIT; ++it) {
            float r = sa[it].x - sb[it].x;
            float q = sa[it].y - sb[it].y;
            sum += r * r + q * q;
        }
    }

    #pragma unroll
    for (int off = 32; off; off >>= 1) sum += __shfl_down(sum, off, 64);
    if (lane == 0) wsum[wid] = sum;
    __syncthreads();
    if (tid == 0) {
        float t = wsum[0] + wsum[1] + wsum[2] + wsum[3];
        atomicAdd(acc, (double)t);
        __threadfence();
        int prev = atomicAdd(done, 1);
        if (prev == NBLK - 1) {
            double total = atomicAdd(acc, 0.0);
            out[0] = (float)(total / (double)((size_t)BC * LL));
        }
    }
}

// ---------- fallback (round-1 kernel) if workspace too small ----------
constexpr int FCHUNKS = 32;
constexpr int FCHUNK  = (LL + FCHUNKS - 1) / FCHUNKS;

__global__ __launch_bounds__(256) void mse_fallback(
    const float* __restrict__ i_f, const float* __restrict__ i_s,
    const float* __restrict__ t_f, const float* __restrict__ t_s,
    const int*  __restrict__ xi,  const float* __restrict__ ks,
    double* __restrict__ acc)
{
    const int bc    = blockIdx.x / FCHUNKS;
    const int chunk = blockIdx.x % FCHUNKS;
    const int l0 = chunk * FCHUNK;
    const int l1 = (l0 + FCHUNK < LL) ? (l0 + FCHUNK) : LL;

    const float2* isv = (const float2*)i_s + (size_t)bc * LL;
    const float2* tsv = (const float2*)t_s + (size_t)bc * LL;
    const float2* ifv = (const float2*)i_f + (size_t)bc * NF;
    const float2* tfv = (const float2*)t_f + (size_t)bc * NF;
    const int2*   xiv = (const int2*)xi;
    const float2* ksv = (const float2*)ks;

    float sum = 0.f;
    for (int l = l0 + (int)threadIdx.x; l < l1; l += 256) {
        float2 si = isv[l], st = tsv[l];
        float gr = si.x - st.x, gi = si.y - st.y;
        float2 k = ksv[l];
        if (!(k.x > 0.f) && !(k.y > 0.f)) {
            int2 idx = xiv[l];
            float2 tf0 = tfv[idx.x], if0 = ifv[idx.x];
            float2 tf1 = tfv[idx.y], if1 = ifv[idx.y];
            float f0r = if0.x - tf0.x, f0i = if0.y - tf0.y;
            float f1r = if1.x - tf1.x, f1i = if1.y - tf1.y;
            gr -= f0r * tf1.x + f0i * tf1.y;
            gi -= f0i * tf1.x - f0r * tf1.y;
            gr -= tf0.x * f1r + tf0.y * f1i;
            gi -= tf0.y * f1r - tf0.x * f1i;
        }
        sum += gr * gr + gi * gi;
    }
    #pragma unroll
    for (int off = 32; off; off >>= 1) sum += __shfl_down(sum, off, 64);
    __shared__ float ws[4];
    const int lane = threadIdx.x & 63, wwid = threadIdx.x >> 6;
    if (lane == 0) ws[wwid] = sum;
    __syncthreads();
    if (threadIdx.x == 0) {
        float t = ws[0] + ws[1] + ws[2] + ws[3];
        atomicAdd(acc, (double)t);
    }
}

__global__ void mse_finalize(const double* __restrict__ acc, float* __restrict__ out)
{
    out[0] = (float)(acc[0] / (double)((size_t)BC * LL));
}

extern "C" void kernel_launch(void* const* d_in, const int* in_sizes, int n_in,
                              void* d_out, int out_size, void* d_ws, size_t ws_size,
                              hipStream_t stream)
{
    const float* i_f = (const float*)d_in[0];
    const float* i_s = (const float*)d_in[1];
    const float* t_f = (const float*)d_in[2];
    const float* t_s = (const float*)d_in[3];
    const int*   xi  = (const int*)d_in[4];
    const float* ks  = (const float*)d_in[5];
    float* out = (float*)d_out;

    char* ws = (char*)d_ws;
    double* acc = (double*)(ws + WS_ACC);
    int*   done = (int*)(ws + WS_DONE);

    if (ws_size >= WS_NEED) {
        f32x4* tbl = (f32x4*)(ws + WS_TBL);
        prep_t<<<TBLK, 256, 0, stream>>>((const float2*)i_f, (const float2*)t_f, tbl, acc, done);
        mse_main4<<<NBLK, BLOCK, 0, stream>>>(
            i_s, t_s, (const int2*)xi, (const f32x2*)ks, tbl, acc, done, out);
    } else {
        (void)hipMemsetAsync(ws, 0, 16, stream);
        mse_fallback<<<BC * FCHUNKS, 256, 0, stream>>>(
            i_f, i_s, t_f, t_s, xi, ks, acc);
        mse_finalize<<<1, 1, 0, stream>>>(acc, out);
    }
}

// Round 6
// 81.624 us; speedup vs baseline: 1.1777x; 1.0194x over previous
//
#include <hip/hip_runtime.h>

// Problem constants (from reference)
#define NF 10000
#define LL 100000

typedef float f32x2 __attribute__((ext_vector_type(2)));
typedef float f32x4 __attribute__((ext_vector_type(4)));

constexpr int BC    = 64;                    // B*C
constexpr int TL    = 64;                    // l's per main block
constexpr int NBLK  = (LL + TL - 1) / TL;    // 1563
constexpr int BLOCK = 512;                   // 8 waves
constexpr int NW    = BLOCK / 64;            // 8
constexpr int NIT   = BC / NW;               // 8 bc-iterations per thread
constexpr int CSTR  = 65;                    // corr row: slots 0..63 + zero col 64

constexpr int TNF   = 16;                    // nf rows per prep block
constexpr int TBLK  = NF / TNF;              // 625 (exact)

// workspace layout
constexpr size_t WS_ACC  = 0;     // double
constexpr size_t WS_DONE = 8;     // int
constexpr size_t WS_TBL  = 256;   // NF*64 float4 = 10,240,000 B
constexpr size_t WS_NEED = WS_TBL + (size_t)NF * BC * 16;

// ---------- prep: transpose (fgap, t_f) into packed [nf][bc] float4 rows ----------
__global__ __launch_bounds__(256) void prep_t(
    const float2* __restrict__ i_f, const float2* __restrict__ t_f,
    f32x4* __restrict__ tbl, double* __restrict__ acc, int* __restrict__ done)
{
    __shared__ f32x4 t4[BC][TNF + 1];
    const int nf0 = blockIdx.x * TNF;
    const int tid = threadIdx.x;

    if (blockIdx.x == 0 && tid == 0) { *acc = 0.0; *done = 0; }

    const int c = tid & 15;          // nf within tile
    const int r = tid >> 4;          // bc start (0..15)
    for (int bc = r; bc < BC; bc += 16) {
        float2 iv = i_f[(size_t)bc * NF + nf0 + c];
        float2 tv = t_f[(size_t)bc * NF + nf0 + c];
        t4[bc][c] = (f32x4){iv.x - tv.x, iv.y - tv.y, tv.x, tv.y};
    }
    __syncthreads();
    const int lane = tid & 63;       // bc
    const int w    = tid >> 6;       // 0..3
    for (int j = w; j < TNF; j += 4)
        tbl[(size_t)(nf0 + j) * BC + lane] = t4[lane][j];
}

// ---------- main: 8-wave, ballot classify, coalesced gather, branch-free stream ----------
__global__ __launch_bounds__(BLOCK) void mse_main5(
    const float* __restrict__ i_s, const float* __restrict__ t_s,
    const int2*  __restrict__ xi,  const f32x2* __restrict__ ks,
    const f32x4* __restrict__ tbl,
    double* __restrict__ acc, int* __restrict__ done, float* __restrict__ out)
{
    __shared__ f32x2 corr[BC * CSTR];   // [bc][slot], slot 64 = zero column
    __shared__ int2  xi_list[TL];
    __shared__ int   pos[TL];
    __shared__ int   cnt_s;
    __shared__ float wsum[NW];

    const int l0   = blockIdx.x * TL;
    const int tlb  = min(TL, LL - l0);
    const int tid  = threadIdx.x;
    const int lane = tid & 63;
    const int wid  = tid >> 6;
    const bool live = lane < tlb;
    const int lc   = l0 + (live ? lane : (tlb - 1));   // clamped l (always in-bounds)

    // wave 0: ballot classify + compaction; wave 1: zero the dummy corr column
    if (wid == 0) {
        f32x2 kv = {1.f, 1.f};
        int2  idxv = {0, 0};
        if (live) { kv = ks[l0 + lane]; idxv = xi[l0 + lane]; }
        const bool active = live && !(kv.x > 0.f) && !(kv.y > 0.f);
        const unsigned long long m = __ballot(active);
        const int slot = __popcll(m & ((1ull << lane) - 1ull));
        pos[lane] = active ? slot : -1;
        if (active) xi_list[slot] = idxv;
        if (lane == 0) cnt_s = (int)__popcll(m);
    } else if (wid == 1) {
        corr[lane * CSTR + 64] = (f32x2){0.f, 0.f};
    }
    __syncthreads();

    // gather: one wave per active slot reads 2 coalesced 1KB table rows
    const int nact = cnt_s;
    for (int a = wid; a < nact; a += NW) {
        int2 idx = xi_list[a];
        f32x4 r0 = tbl[(size_t)idx.x * BC + lane];  // (f0, tf0)
        f32x4 r1 = tbl[(size_t)idx.y * BC + lane];  // (f1, tf1)
        // corr = cmul_conj(f0,tf1) + cmul_conj(tf0,f1)
        float cr = r0.x * r1.z + r0.y * r1.w + r0.z * r1.x + r0.w * r1.y;
        float ci = r0.y * r1.z - r0.x * r1.w + r0.w * r1.x - r0.z * r1.y;
        corr[lane * CSTR + a] = (f32x2){cr, ci};
    }
    __syncthreads();

    // stream: issue ALL 16 loads in one straight-line window, then consume.
    // Inactive/dead lanes read slot 64 (zero, broadcast).
    const int myslot = (live && pos[lane] >= 0) ? pos[lane] : 64;
    f32x2 va[NIT], vb[NIT];
    #pragma unroll
    for (int it = 0; it < NIT; ++it) {
        const size_t off = ((size_t)(wid + it * NW) * LL + lc) * 2;
        va[it] = *(const f32x2*)(i_s + off);
        vb[it] = *(const f32x2*)(t_s + off);
    }
    float sum = 0.f;
    #pragma unroll
    for (int it = 0; it < NIT; ++it) {
        f32x2 cc = corr[(wid + it * NW) * CSTR + myslot];
        float r = (va[it].x - vb[it].x) - cc.x;
        float q = (va[it].y - vb[it].y) - cc.y;
        sum += r * r + q * q;
    }
    if (!live) sum = 0.f;

    #pragma unroll
    for (int off = 32; off; off >>= 1) sum += __shfl_down(sum, off, 64);
    if (lane == 0) wsum[wid] = sum;
    __syncthreads();
    if (tid == 0) {
        float t = 0.f;
        #pragma unroll
        for (int i = 0; i < NW; ++i) t += wsum[i];
        atomicAdd(acc, (double)t);
        __threadfence();
        int prev = atomicAdd(done, 1);
        if (prev == NBLK - 1) {
            __threadfence();
            double total = atomicAdd(acc, 0.0);
            out[0] = (float)(total / (double)((size_t)BC * LL));
        }
    }
}

// ---------- fallback (round-1 kernel) if workspace too small ----------
constexpr int FCHUNKS = 32;
constexpr int FCHUNK  = (LL + FCHUNKS - 1) / FCHUNKS;

__global__ __launch_bounds__(256) void mse_fallback(
    const float* __restrict__ i_f, const float* __restrict__ i_s,
    const float* __restrict__ t_f, const float* __restrict__ t_s,
    const int*  __restrict__ xi,  const float* __restrict__ ks,
    double* __restrict__ acc)
{
    const int bc    = blockIdx.x / FCHUNKS;
    const int chunk = blockIdx.x % FCHUNKS;
    const int l0 = chunk * FCHUNK;
    const int l1 = (l0 + FCHUNK < LL) ? (l0 + FCHUNK) : LL;

    const float2* isv = (const float2*)i_s + (size_t)bc * LL;
    const float2* tsv = (const float2*)t_s + (size_t)bc * LL;
    const float2* ifv = (const float2*)i_f + (size_t)bc * NF;
    const float2* tfv = (const float2*)t_f + (size_t)bc * NF;
    const int2*   xiv = (const int2*)xi;
    const float2* ksv = (const float2*)ks;

    float sum = 0.f;
    for (int l = l0 + (int)threadIdx.x; l < l1; l += 256) {
        float2 si = isv[l], st = tsv[l];
        float gr = si.x - st.x, gi = si.y - st.y;
        float2 k = ksv[l];
        if (!(k.x > 0.f) && !(k.y > 0.f)) {
            int2 idx = xiv[l];
            float2 tf0 = tfv[idx.x], if0 = ifv[idx.x];
            float2 tf1 = tfv[idx.y], if1 = ifv[idx.y];
            float f0r = if0.x - tf0.x, f0i = if0.y - tf0.y;
            float f1r = if1.x - tf1.x, f1i = if1.y - tf1.y;
            gr -= f0r * tf1.x + f0i * tf1.y;
            gi -= f0i * tf1.x - f0r * tf1.y;
            gr -= tf0.x * f1r + tf0.y * f1i;
            gi -= tf0.y * f1r - tf0.x * f1i;
        }
        sum += gr * gr + gi * gi;
    }
    #pragma unroll
    for (int off = 32; off; off >>= 1) sum += __shfl_down(sum, off, 64);
    __shared__ float ws[4];
    const int lane = threadIdx.x & 63, wwid = threadIdx.x >> 6;
    if (lane == 0) ws[wwid] = sum;
    __syncthreads();
    if (threadIdx.x == 0) {
        float t = ws[0] + ws[1] + ws[2] + ws[3];
        atomicAdd(acc, (double)t);
    }
}

__global__ void mse_finalize(const double* __restrict__ acc, float* __restrict__ out)
{
    out[0] = (float)(acc[0] / (double)((size_t)BC * LL));
}

extern "C" void kernel_launch(void* const* d_in, const int* in_sizes, int n_in,
                              void* d_out, int out_size, void* d_ws, size_t ws_size,
                              hipStream_t stream)
{
    const float* i_f = (const float*)d_in[0];
    const float* i_s = (const float*)d_in[1];
    const float* t_f = (const float*)d_in[2];
    const float* t_s = (const float*)d_in[3];
    const int*   xi  = (const int*)d_in[4];
    const float* ks  = (const float*)d_in[5];
    float* out = (float*)d_out;

    char* ws = (char*)d_ws;
    double* acc = (double*)(ws + WS_ACC);
    int*   done = (int*)(ws + WS_DONE);

    if (ws_size >= WS_NEED) {
        f32x4* tbl = (f32x4*)(ws + WS_TBL);
        prep_t<<<TBLK, 256, 0, stream>>>((const float2*)i_f, (const float2*)t_f, tbl, acc, done);
        mse_main5<<<NBLK, BLOCK, 0, stream>>>(
            i_s, t_s, (const int2*)xi, (const f32x2*)ks, tbl, acc, done, out);
    } else {
        (void)hipMemsetAsync(ws, 0, 16, stream);
        mse_fallback<<<BC * FCHUNKS, 256, 0, stream>>>(
            i_f, i_s, t_f, t_s, xi, ks, acc);
        mse_finalize<<<1, 1, 0, stream>>>(acc, out);
    }
}